// Round 1
// baseline (165.406 us; speedup 1.0000x reference)
//
#include <hip/hip_runtime.h>

// Problem constants (match the JAX reference)
constexpr int BATCH      = 256;
constexpr int T          = 100;
constexpr int J          = 32;
constexpr int CC         = 3;
constexpr int EDGES      = 101;
constexpr int NBINS      = 100;
constexpr int NPAIR      = (J * (J - 1)) / 2;   // 496 unordered pairs
constexpr int PAIRS_TOTAL = T * NPAIR;          // 49600 per dataset per row
constexpr int ROW_FLOATS = T * J * CC;          // 9600 floats per row
constexpr int NREP       = 8;                   // histogram replicas
constexpr int NTHREADS   = 256;
constexpr float EPSF     = 1e-8f;
constexpr float NTOT     = 102400.0f;           // T*J*J = counts.sum()

// Exact searchsorted(edges, x, side='right') - 1, clipped to [0, NBINS-1].
// Guess via approximate inverse width, then exact fixup against LDS edges.
__device__ __forceinline__ int bin_of(float x, const float* __restrict__ e, float invw) {
    int i = (int)(x * invw);
    i = i < 0 ? 0 : (i > NBINS - 1 ? NBINS - 1 : i);
    while (i < NBINS - 1 && x >= e[i + 1]) ++i;
    while (i > 0 && x < e[i]) --i;
    return i;
}

__global__ __launch_bounds__(NTHREADS)
void jsd_kernel(const float* __restrict__ g1all,
                const float* __restrict__ g2all,
                float* __restrict__ out)
{
#pragma clang fp contract(off)
    __shared__ float s1[ROW_FLOATS];
    __shared__ float s2[ROW_FLOATS];
    __shared__ unsigned short lut[NPAIR];
    __shared__ float edg[EDGES];
    __shared__ unsigned int h1[NREP][NBINS];
    __shared__ unsigned int h2[NREP][NBINS];
    __shared__ float sred[4];
    __shared__ float sterm[NBINS];
    __shared__ float s_mx, s_invw;

    const int tid = threadIdx.x;
    const int row = blockIdx.x;
    const float* g1 = g1all + (size_t)row * ROW_FLOATS;
    const float* g2 = g2all + (size_t)row * ROW_FLOATS;

    // Stage both rows into LDS (coalesced), zero histograms, build pair LUT.
    for (int k = tid; k < ROW_FLOATS; k += NTHREADS) { s1[k] = g1[k]; s2[k] = g2[k]; }
    for (int k = tid; k < NREP * NBINS; k += NTHREADS) {
        (&h1[0][0])[k] = 0u;
        (&h2[0][0])[k] = 0u;
    }
    if (tid == 0) {
        int p = 0;
        for (int a = 0; a < J; ++a)
            for (int c = a + 1; c < J; ++c)
                lut[p++] = (unsigned short)((a << 5) | c);
    }
    __syncthreads();

    // ---- Pass A: max squared distance over BOTH datasets (sqrt is monotone,
    // so max(sqrt(s)) == sqrt(max(s)) with correctly-rounded sqrt). min == 0
    // exactly (diagonal pairs), so edges depend only on mx.
    float vmax = 0.0f;
    for (int p = tid; p < PAIRS_TOTAL; p += NTHREADS) {
        const int t  = p / NPAIR;
        const int r  = p - t * NPAIR;
        const int jj = lut[r];
        const int ia = (t * J + (jj >> 5)) * CC;
        const int ib = (t * J + (jj & 31)) * CC;

        float ax = s1[ia + 0] - s1[ib + 0];
        float ay = s1[ia + 1] - s1[ib + 1];
        float az = s1[ia + 2] - s1[ib + 2];
        float sA = ax * ax + ay * ay + az * az;   // ((x^2+y^2)+z^2), no FMA

        float bx = s2[ia + 0] - s2[ib + 0];
        float by = s2[ia + 1] - s2[ib + 1];
        float bz = s2[ia + 2] - s2[ib + 2];
        float sB = bx * bx + by * by + bz * bz;

        vmax = fmaxf(vmax, fmaxf(sA, sB));
    }
    // wave64 + cross-wave reduction
    for (int off = 32; off > 0; off >>= 1)
        vmax = fmaxf(vmax, __shfl_down(vmax, off, 64));
    if ((tid & 63) == 0) sred[tid >> 6] = vmax;
    __syncthreads();
    if (tid == 0) {
        float m = fmaxf(fmaxf(sred[0], sred[1]), fmaxf(sred[2], sred[3]));
        float mx = __fsqrt_rn(m);
        s_mx = mx;
        s_invw = 100.0f / mx;   // approximate — bin_of() fixup makes binning exact
    }
    __syncthreads();

    // edges[i] = mn*w0[i] + mx*w1[i] with mn==0 → mx*w1[i];
    // w1[i] = f32(i)*f32(0.01) (JAX linspace in f32), endpoint pinned to 1.0.
    if (tid < EDGES) {
        float w1 = (tid == EDGES - 1) ? 1.0f : ((float)tid * 0.01f);
        edg[tid] = s_mx * w1;
    }
    __syncthreads();

    // ---- Pass B: recompute distances, histogram with weight 2 (unordered pairs).
    const float invw = s_invw;
    for (int p = tid; p < PAIRS_TOTAL; p += NTHREADS) {
        const int t  = p / NPAIR;
        const int r  = p - t * NPAIR;
        const int jj = lut[r];
        const int ia = (t * J + (jj >> 5)) * CC;
        const int ib = (t * J + (jj & 31)) * CC;

        float ax = s1[ia + 0] - s1[ib + 0];
        float ay = s1[ia + 1] - s1[ib + 1];
        float az = s1[ia + 2] - s1[ib + 2];
        float sA = ax * ax + ay * ay + az * az;
        float xA = __fsqrt_rn(sA);

        float bx = s2[ia + 0] - s2[ib + 0];
        float by = s2[ia + 1] - s2[ib + 1];
        float bz = s2[ia + 2] - s2[ib + 2];
        float sB = bx * bx + by * by + bz * bz;
        float xB = __fsqrt_rn(sB);

        const int rep = tid & (NREP - 1);
        atomicAdd(&h1[rep][bin_of(xA, edg, invw)], 2u);
        atomicAdd(&h2[rep][bin_of(xB, edg, invw)], 2u);
    }
    __syncthreads();

    // ---- Final: densities + JSD terms per bin, then serial sum (100 adds).
    if (tid < NBINS) {
        unsigned int c1 = 0, c2 = 0;
        for (int r = 0; r < NREP; ++r) { c1 += h1[r][tid]; c2 += h2[r][tid]; }
        if (tid == 0) { c1 += T * J; c2 += T * J; }   // diagonal zeros → bin 0

        float w   = edg[tid + 1] - edg[tid];          // jnp.diff(edges)
        float den = __fmul_rn(NTOT, w);
        float px  = __fdiv_rn((float)c1, den);
        float qx  = __fdiv_rn((float)c2, den);
        float m   = (px + qx) * 0.5f;
        float lm  = logf(m + EPSF);
        float term = px * (logf(px + EPSF) - lm) + qx * (logf(qx + EPSF) - lm);
        sterm[tid] = term;
    }
    __syncthreads();
    if (tid == 0) {
        float acc = 0.0f;
        for (int i = 0; i < NBINS; ++i) acc += sterm[i];
        out[row] = acc * 0.5f;
    }
}

extern "C" void kernel_launch(void* const* d_in, const int* in_sizes, int n_in,
                              void* d_out, int out_size, void* d_ws, size_t ws_size,
                              hipStream_t stream) {
    const float* d1 = (const float*)d_in[0];
    const float* d2 = (const float*)d_in[1];
    float* out = (float*)d_out;
    jsd_kernel<<<BATCH, NTHREADS, 0, stream>>>(d1, d2, out);
}

// Round 2
// 59.488 us; speedup vs baseline: 2.7805x; 2.7805x over previous
//
#include <hip/hip_runtime.h>

// Problem constants (match the JAX reference)
constexpr int BATCH       = 256;
constexpr int T           = 100;
constexpr int J           = 32;
constexpr int CC          = 3;
constexpr int EDGES       = 101;
constexpr int NBINS       = 100;
constexpr int NPAIR       = (J * (J - 1)) / 2;   // 496 unordered pairs
constexpr int PAIRS_TOTAL = T * NPAIR;           // 49600 per dataset per row
constexpr int NPOINTS     = T * J;               // 3200 points per row
constexpr int ROW_FLOATS  = NPOINTS * CC;        // 9600 floats per row
constexpr int NREP        = 16;                  // histogram replicas
constexpr int HSTRIDE     = 101;                 // replica stride (bank spread)
constexpr int NTHREADS    = 1024;                // 16 waves -> 50% occupancy
constexpr int NWAVES      = NTHREADS / 64;
constexpr float EPSF      = 1e-8f;
constexpr float NTOT      = 102400.0f;           // T*J*J = counts.sum()

// Exact searchsorted(edges, x, side='right') - 1, clipped to [0, NBINS-1].
// Guess via approximate inverse width, then exact fixup against LDS edges.
__device__ __forceinline__ int bin_of(float x, const float* __restrict__ e, float invw) {
    int i = (int)(x * invw);
    i = i < 0 ? 0 : (i > NBINS - 1 ? NBINS - 1 : i);
    while (i < NBINS - 1 && x >= e[i + 1]) ++i;
    while (i > 0 && x < e[i]) --i;
    return i;
}

__global__ __launch_bounds__(NTHREADS)
void jsd_kernel(const float* __restrict__ g1all,
                const float* __restrict__ g2all,
                float* __restrict__ out)
{
#pragma clang fp contract(off)
    // Split point layout: (x,y) as float2 (ds_read_b64) + z (ds_read_b32)
    __shared__ float2 s1xy[NPOINTS];
    __shared__ float  s1z [NPOINTS];
    __shared__ float2 s2xy[NPOINTS];
    __shared__ float  s2z [NPOINTS];
    __shared__ unsigned short lut[NPAIR];
    __shared__ float edg[EDGES];
    __shared__ unsigned int h1[NREP][HSTRIDE];
    __shared__ unsigned int h2[NREP][HSTRIDE];
    __shared__ float sred[NWAVES];
    __shared__ float sterm[NBINS];
    __shared__ float s_mx, s_invw;

    const int tid = threadIdx.x;
    const int row = blockIdx.x;
    const float* g1 = g1all + (size_t)row * ROW_FLOATS;
    const float* g2 = g2all + (size_t)row * ROW_FLOATS;

    // Stage both rows into LDS (split layout), zero histograms, build pair LUT.
    for (int k = tid; k < NPOINTS; k += NTHREADS) {
        s1xy[k] = make_float2(g1[3 * k + 0], g1[3 * k + 1]);
        s1z [k] = g1[3 * k + 2];
        s2xy[k] = make_float2(g2[3 * k + 0], g2[3 * k + 1]);
        s2z [k] = g2[3 * k + 2];
    }
    for (int k = tid; k < NREP * HSTRIDE; k += NTHREADS) {
        (&h1[0][0])[k] = 0u;
        (&h2[0][0])[k] = 0u;
    }
    if (tid < J) {
        const int a = tid;
        int p = a * (2 * J - a - 1) / 2;   // triangular base offset
        for (int c = a + 1; c < J; ++c)
            lut[p++] = (unsigned short)((a << 5) | c);
    }
    __syncthreads();

    // ---- Pass A: max squared distance over BOTH datasets (sqrt is monotone,
    // so max(sqrt(s)) == sqrt(max(s)) with correctly-rounded sqrt). min == 0
    // exactly (diagonal pairs), so edges depend only on mx.
    float vmax = 0.0f;
    for (int p = tid; p < PAIRS_TOTAL; p += NTHREADS) {
        const int t  = p / NPAIR;
        const int r  = p - t * NPAIR;
        const int jj = lut[r];
        const int ia = t * J + (jj >> 5);
        const int ib = t * J + (jj & 31);

        float2 a1 = s1xy[ia], b1 = s1xy[ib];
        float  az1 = s1z[ia], bz1 = s1z[ib];
        float ax = a1.x - b1.x;
        float ay = a1.y - b1.y;
        float az = az1 - bz1;
        float sA = ax * ax + ay * ay + az * az;   // ((x^2+y^2)+z^2), no FMA

        float2 a2 = s2xy[ia], b2 = s2xy[ib];
        float  az2 = s2z[ia], bz2 = s2z[ib];
        float bx = a2.x - b2.x;
        float by = a2.y - b2.y;
        float bz = az2 - bz2;
        float sB = bx * bx + by * by + bz * bz;

        vmax = fmaxf(vmax, fmaxf(sA, sB));
    }
    // wave64 + cross-wave reduction
    for (int off = 32; off > 0; off >>= 1)
        vmax = fmaxf(vmax, __shfl_down(vmax, off, 64));
    if ((tid & 63) == 0) sred[tid >> 6] = vmax;
    __syncthreads();
    if (tid == 0) {
        float m = sred[0];
        for (int w = 1; w < NWAVES; ++w) m = fmaxf(m, sred[w]);
        float mx = __fsqrt_rn(m);
        s_mx = mx;
        s_invw = 100.0f / mx;   // approximate — bin_of() fixup makes binning exact
    }
    __syncthreads();

    // edges[i] = mn*w0[i] + mx*w1[i] with mn==0 → mx*w1[i];
    // w1[i] = f32(i)*f32(0.01) (JAX linspace in f32), endpoint pinned to 1.0.
    if (tid < EDGES) {
        float w1 = (tid == EDGES - 1) ? 1.0f : ((float)tid * 0.01f);
        edg[tid] = s_mx * w1;
    }
    __syncthreads();

    // ---- Pass B: recompute distances, histogram with weight 2 (unordered pairs).
    const float invw = s_invw;
    const int rep = tid & (NREP - 1);
    for (int p = tid; p < PAIRS_TOTAL; p += NTHREADS) {
        const int t  = p / NPAIR;
        const int r  = p - t * NPAIR;
        const int jj = lut[r];
        const int ia = t * J + (jj >> 5);
        const int ib = t * J + (jj & 31);

        float2 a1 = s1xy[ia], b1 = s1xy[ib];
        float  az1 = s1z[ia], bz1 = s1z[ib];
        float ax = a1.x - b1.x;
        float ay = a1.y - b1.y;
        float az = az1 - bz1;
        float sA = ax * ax + ay * ay + az * az;
        float xA = __fsqrt_rn(sA);

        float2 a2 = s2xy[ia], b2 = s2xy[ib];
        float  az2 = s2z[ia], bz2 = s2z[ib];
        float bx = a2.x - b2.x;
        float by = a2.y - b2.y;
        float bz = az2 - bz2;
        float sB = bx * bx + by * by + bz * bz;
        float xB = __fsqrt_rn(sB);

        atomicAdd(&h1[rep][bin_of(xA, edg, invw)], 2u);
        atomicAdd(&h2[rep][bin_of(xB, edg, invw)], 2u);
    }
    __syncthreads();

    // ---- Final: densities + JSD terms per bin, then serial sum (100 adds,
    // kept serial to match the reference bit-exactly — absmax was 0.0).
    if (tid < NBINS) {
        unsigned int c1 = 0, c2 = 0;
        for (int r = 0; r < NREP; ++r) { c1 += h1[r][tid]; c2 += h2[r][tid]; }
        if (tid == 0) { c1 += T * J; c2 += T * J; }   // diagonal zeros → bin 0

        float w   = edg[tid + 1] - edg[tid];          // jnp.diff(edges)
        float den = __fmul_rn(NTOT, w);
        float px  = __fdiv_rn((float)c1, den);
        float qx  = __fdiv_rn((float)c2, den);
        float m   = (px + qx) * 0.5f;
        float lm  = logf(m + EPSF);
        float term = px * (logf(px + EPSF) - lm) + qx * (logf(qx + EPSF) - lm);
        sterm[tid] = term;
    }
    __syncthreads();
    if (tid == 0) {
        float acc = 0.0f;
        for (int i = 0; i < NBINS; ++i) acc += sterm[i];
        out[row] = acc * 0.5f;
    }
}

extern "C" void kernel_launch(void* const* d_in, const int* in_sizes, int n_in,
                              void* d_out, int out_size, void* d_ws, size_t ws_size,
                              hipStream_t stream) {
    const float* d1 = (const float*)d_in[0];
    const float* d2 = (const float*)d_in[1];
    float* out = (float*)d_out;
    jsd_kernel<<<BATCH, NTHREADS, 0, stream>>>(d1, d2, out);
}